// Round 3
// baseline (450.531 us; speedup 1.0000x reference)
//
#include <hip/hip_runtime.h>
#include <math.h>

#define NPTS 8192
#define NB   4
#define KNN  16
#define NC   64
#define QCAP 96   // per-(query,quarter) survivor capacity

// ---------------------------------------------------------------------------
// prep (2 phases as separate blocks):
//  phase 0 (source pts): cand[b][m]=(x,y,z,|p|^2); GF[b][m][o]=(Gk,F2)
//  phase 1 (center pts): CF[b][n][o]=(Gc+bg, F1+bf)
// ---------------------------------------------------------------------------
__global__ __launch_bounds__(256) void prep_kernel(
    const float* __restrict__ xyz, const float* __restrict__ xyz_s,
    const float* __restrict__ fea, const float* __restrict__ fea_s,
    const float* __restrict__ Wg,  const float* __restrict__ bg,
    const float* __restrict__ Wf,  const float* __restrict__ bf,
    float4* __restrict__ cand, float2* __restrict__ GF, float2* __restrict__ CF)
{
    __shared__ float wt[64 * 64];   // [c][o]
    __shared__ float gw[3 * 64];    // [d][o]
    __shared__ float bias2[2 * 64]; // [g|f][o]
    int tid   = threadIdx.x;
    int phase = blockIdx.x & 1;
    int g     = (blockIdx.x >> 1) * 256 + tid;
    int b     = g >> 13, m = g & (NPTS - 1);

    for (int i = tid; i < 4096; i += 256) {
        int o = i >> 6, c = i & 63;
        wt[c * 64 + o] = Wf[o * 128 + (phase ? c : 64 + c)];
    }
    if (tid < 192) {
        int d = tid >> 6, o = tid & 63;
        gw[d * 64 + o] = phase ? (Wg[o * 10 + 1 + d] + Wg[o * 10 + 7 + d])
                               : (Wg[o * 10 + 4 + d] - Wg[o * 10 + 7 + d]);
    }
    if (tid < 64) {
        bias2[tid]      = phase ? bg[tid] : 0.f;
        bias2[64 + tid] = phase ? bf[tid] : 0.f;
    }
    __syncthreads();

    const float* P = phase ? xyz : xyz_s;
    const float* F = phase ? fea : fea_s;
    float x = P[(b * 3 + 0) * NPTS + m];
    float y = P[(b * 3 + 1) * NPTS + m];
    float z = P[(b * 3 + 2) * NPTS + m];
    if (!phase) cand[b * NPTS + m] = make_float4(x, y, z, x * x + y * y + z * z);

    float acc[NC];
    #pragma unroll
    for (int o = 0; o < NC; o++) acc[o] = 0.f;
    for (int c = 0; c < NC; c++) {
        float v = F[(size_t)(b * NC + c) * NPTS + m];
        const float4* w4 = (const float4*)&wt[c * 64];
        #pragma unroll
        for (int o4 = 0; o4 < 16; o4++) {
            float4 w = w4[o4];
            acc[o4*4+0] = fmaf(w.x, v, acc[o4*4+0]);
            acc[o4*4+1] = fmaf(w.y, v, acc[o4*4+1]);
            acc[o4*4+2] = fmaf(w.z, v, acc[o4*4+2]);
            acc[o4*4+3] = fmaf(w.w, v, acc[o4*4+3]);
        }
    }
    float2* O = (phase ? CF : GF) + ((size_t)(b * NPTS + m)) * NC;
    #pragma unroll
    for (int o = 0; o < NC; o++) {
        float geo = fmaf(gw[o], x, fmaf(gw[64 + o], y, gw[128 + o] * z));
        O[o] = make_float2(geo + bias2[o], acc[o] + bias2[64 + o]);
    }
}

// ---------------------------------------------------------------------------
// knn_fused: block = 4 waves, 64 queries (lane = query), candidates streamed
// wave-uniformly (scalar loads). Wave w owns candidate quarter w (2048).
//  T: sample 1024/quarter, 16 slice-maxima per lane -> LDS transpose
//  B: per-query 64-lane bitonic over 64 slice maxima -> tau (16th largest)
//  F: full quarter scan, push sc>=tau local idx (u16) into LDS, no atomics
//  S: wave 0, thread-per-query sorted-insert of packed u64 over survivors
// ---------------------------------------------------------------------------
__global__ __launch_bounds__(256) void knn_fused(
    const float4* __restrict__ cand, const float* __restrict__ xyz,
    int* __restrict__ idxout)
{
    __shared__ float maxima[64][66];                 // [query][slice]
    __shared__ unsigned short surv[4][QCAP][64];     // [quarter][pos][query]
    __shared__ int   cntL[4][64];                    // [quarter][query]
    __shared__ float tauL[64];

    int tid = threadIdx.x;
    int lane = tid & 63, w = tid >> 6;
    int wq = __builtin_amdgcn_readfirstlane(w);
    int b = blockIdx.x >> 7;
    int qbase = (blockIdx.x & 127) << 6;
    int q = qbase + lane;

    float qx = xyz[(b * 3 + 0) * NPTS + q];
    float qy = xyz[(b * 3 + 1) * NPTS + q];
    float qz = xyz[(b * 3 + 2) * NPTS + q];
    float ax = 2.f * qx, ay = 2.f * qy, az = 2.f * qz;

    const float4* cq = cand + b * NPTS + wq * 2048;  // this wave's quarter

    // ---- T: sampled slice maxima (first 1024 of quarter, 16 slices of 64) ----
    for (int sl = 0; sl < 16; ++sl) {
        float mm = -3.0e38f;
        #pragma unroll 8
        for (int j = 0; j < 64; ++j) {
            float4 c = cq[sl * 64 + j];
            float sc = fmaf(ax, c.x, fmaf(ay, c.y, fmaf(az, c.z, -c.w)));
            mm = fmaxf(mm, sc);
        }
        maxima[lane][wq * 16 + sl] = mm;
    }
    __syncthreads();

    // ---- B: per-query bitonic over 64 slice maxima; lane 48 = 16th largest ----
    for (int qq = wq * 16; qq < wq * 16 + 16; ++qq) {
        float m = maxima[qq][lane];
        #pragma unroll
        for (int k = 2; k <= 64; k <<= 1) {
            #pragma unroll
            for (int j = k >> 1; j > 0; j >>= 1) {
                float o = __shfl_xor(m, j);
                bool up = ((lane & k) == 0);
                bool lower = ((lane & j) == 0);
                m = (up == lower) ? fminf(m, o) : fmaxf(m, o);
            }
        }
        if (lane == 48) tauL[qq] = m;
    }
    __syncthreads();
    float tau = tauL[lane];

    // ---- F: full quarter scan with threshold filter ----
    int cnt = 0;
    #pragma unroll 4
    for (int t = 0; t < 2048; ++t) {
        float4 c = cq[t];
        float sc = fmaf(ax, c.x, fmaf(ay, c.y, fmaf(az, c.z, -c.w)));
        if (sc >= tau && cnt < QCAP) {
            surv[wq][cnt][lane] = (unsigned short)t;
            cnt++;
        }
    }
    cntL[wq][lane] = cnt;
    __syncthreads();

    // ---- S: selection (wave 0 only; thread t = query t) ----
    if (w == 0) {
        const float4* cb = cand + b * NPTS;
        unsigned long long s[KNN];
        #pragma unroll
        for (int j = 0; j < KNN; j++) s[j] = 0ull;

        for (int qq = 0; qq < 4; ++qq) {
            int cl = cntL[qq][lane];
            int vm = cl;
            #pragma unroll
            for (int off = 1; off < 64; off <<= 1)
                vm = max(vm, __shfl_xor(vm, off));
            for (int j = 0; j < vm; ++j) {
                int tl = surv[qq][j][lane];
                int gi = qq * 2048 + tl;
                float4 c = cb[gi];
                float sc = fmaf(ax, c.x, fmaf(ay, c.y, fmaf(az, c.z, -c.w)));
                unsigned u = __float_as_uint(sc);
                u ^= (unsigned)((int)u >> 31) | 0x80000000u;
                unsigned long long key =
                    ((unsigned long long)u << 32) | (unsigned)(8191 - gi);
                if (j < cl && key > s[0]) {
                    bool cj = true;
                    #pragma unroll
                    for (int t = 0; t < KNN; t++) {
                        bool cn = (t < KNN - 1) ? (key > s[t + 1]) : false;
                        unsigned long long fv = cj ? key : s[t];
                        s[t] = cn ? s[t + 1] : fv;
                        cj = cn;
                    }
                }
            }
        }
        int* op = idxout + (((size_t)(b * NPTS + q)) << 4);
        #pragma unroll
        for (int j = 0; j < KNN; j++)
            op[j] = 8191 - (int)(s[j] & 0xFFFFFFFFull);
    }
}

// ---------------------------------------------------------------------------
// fuse: out[b][o][n] = max_k relu(CF.x + wd*d + GF.x) * relu(CF.y + GF.y)
// ---------------------------------------------------------------------------
__global__ __launch_bounds__(256) void fuse_kernel(
    const float* __restrict__ xyz, const float* __restrict__ Wg,
    const float4* __restrict__ cand, const float2* __restrict__ GF,
    const float2* __restrict__ CF, const int* __restrict__ idxb,
    float* __restrict__ out)
{
    __shared__ float tile[16 * 65];
    int tid = threadIdx.x;
    int o = tid & 63, w = tid >> 6;
    int b = blockIdx.x >> 9;
    int nt = (blockIdx.x & 511) << 4;
    float wd = Wg[o * 10];

    for (int i = 0; i < 4; i++) {
        int q = nt + w * 4 + i;
        size_t qb = (size_t)(b * NPTS + q);
        float qx = xyz[(b * 3 + 0) * NPTS + q];
        float qy = xyz[(b * 3 + 1) * NPTS + q];
        float qz = xyz[(b * 3 + 2) * NPTS + q];
        float2 cf = CF[qb * NC + o];
        const int* ip = idxb + qb * KNN;
        float r = 0.f;
        #pragma unroll 4
        for (int kk = 0; kk < KNN; kk++) {
            int mi = ip[kk];
            float4 c = cand[b * NPTS + mi];
            float dx = qx - c.x, dy = qy - c.y, dz = qz - c.z;
            float d = sqrtf(fmaf(dx, dx, fmaf(dy, dy, dz * dz)));
            float2 gf = GF[((size_t)(b * NPTS + mi)) * NC + o];
            float gpre = cf.x + fmaf(wd, d, gf.x);
            float fpre = cf.y + gf.y;
            r = fmaxf(r, fmaxf(gpre, 0.f) * fmaxf(fpre, 0.f));
        }
        tile[(w * 4 + i) * 65 + o] = r;
    }
    __syncthreads();
    int row = tid >> 2, cg = (tid & 3) * 4;
    float* orow = out + (size_t)(b * NC + row) * NPTS + nt + cg;
    #pragma unroll
    for (int j = 0; j < 4; j++) orow[j] = tile[(cg + j) * 65 + row];
}

extern "C" void kernel_launch(void* const* d_in, const int* in_sizes, int n_in,
                              void* d_out, int out_size, void* d_ws, size_t ws_size,
                              hipStream_t stream) {
    const float* xyz   = (const float*)d_in[0];
    const float* xyz_s = (const float*)d_in[1];
    const float* fea   = (const float*)d_in[2];
    const float* fea_s = (const float*)d_in[3];
    const float* Wg    = (const float*)d_in[4];
    const float* bg    = (const float*)d_in[5];
    const float* Wf    = (const float*)d_in[6];
    const float* bf    = (const float*)d_in[7];
    float* out = (float*)d_out;

    float* ws = (float*)d_ws;
    float4* cand = (float4*)ws;                                    // 512 KB
    float2* GF = (float2*)(ws + (size_t)NB * NPTS * 4);            // 16.8 MB
    float2* CF = GF + (size_t)NB * NPTS * NC;                      // 16.8 MB
    int* idxb  = (int*)(CF + (size_t)NB * NPTS * NC);              // 2 MB

    prep_kernel<<<(NB * NPTS / 256) * 2, 256, 0, stream>>>(
        xyz, xyz_s, fea, fea_s, Wg, bg, Wf, bf, cand, GF, CF);
    knn_fused<<<NB * NPTS / 64, 256, 0, stream>>>(cand, xyz, idxb);
    fuse_kernel<<<NB * (NPTS / 16), 256, 0, stream>>>(
        xyz, Wg, cand, GF, CF, idxb, out);
}